// Round 12
// baseline (304.786 us; speedup 1.0000x reference)
//
#include <hip/hip_runtime.h>
#include <hip/hip_cooperative_groups.h>
#include <stdint.h>

namespace cg = cooperative_groups;

// Problem constants (fixed by reference: scores (4, 131072) f32, m=4096, tau=1)
#define BROWS 4
#define NCOLS 131072           // 2^17
#define MREF  4096
#define HIST_BITS 13
#define NBUCK (1 << HIST_BITS) // 8192
#define USHIFT (32 - HIST_BITS)
#define CAP 6144               // candidates per row (<= 4095 + threshold-bucket count)
#define NPART 32
#define PQUOTA 192             // quota spacing (R8-proven: max partition < 1024)
#define PARTCAP 1024           // max bitonic size
#define GRID_BLOCKS 512
#define BLOCK_THREADS 512

__device__ __forceinline__ uint32_t orderable(float f) {
    uint32_t u = __float_as_uint(f);
    return (u & 0x80000000u) ? ~u : (u | 0x80000000u);
}
__device__ __forceinline__ float unorderable(uint32_t u) {
    uint32_t b = (u & 0x80000000u) ? (u & 0x7FFFFFFFu) : ~u;
    return __uint_as_float(b);
}

// R11-proven k_map per-column body (1-col form; called twice, no 4-col loop).
__device__ __forceinline__ void map_one(const float* __restrict__ scr,
                                        const float* __restrict__ srv,
                                        const uint32_t* __restrict__ rir,
                                        int* __restrict__ outr, int col) {
    float s = scr[col];
    // first j with srv[j] <= s (srv descending)
    int lo = 0, hi = MREF;
    while (lo < hi) { int mid = (lo + hi) >> 1; if (srv[mid] <= s) hi = mid; else lo = mid + 1; }
    int p = lo, jmin;
    if (p == 0) jmin = 0;
    else if (p == MREF) jmin = MREF - 1;
    else {
        float dp = fabsf(s - srv[p]);
        float dm = fabsf(s - srv[p - 1]);
        jmin = (dm <= dp) ? (p - 1) : p; // tie -> smaller j (argmax-first)
    }
    float pmax = -fabsf(s - srv[jmin]);
    int jans = jmin;
    // exp-level tie merge: exp(pw - pmax) rounds to 1.0f => equal softmax prob,
    // argmax picks the smallest such j; winner set is contiguous.
    for (int j = jmin - 1; j >= 0; --j) {
        float pw = -fabsf(s - srv[j]);
        if (expf(pw - pmax) == 1.0f) jans = j; else break;
    }
    outr[col] = (int)rir[jans];
}

// R11-proven bitonic network (block-uniform n, size-adaptive P).
#define BITONIC_SORT(PP)                                                        \
    for (uint32_t i = threadIdx.x; i < (uint32_t)(PP); i += blockDim.x)         \
        lds[i] = (i < n) ? seg[i] : ~0ULL;                                      \
    __syncthreads();                                                            \
    for (uint32_t k = 2; k <= (uint32_t)(PP); k <<= 1) {                        \
        for (uint32_t j = k >> 1; j > 0; j >>= 1) {                             \
            for (uint32_t i = threadIdx.x; i < (uint32_t)(PP); i += blockDim.x) { \
                uint32_t ixj = i ^ j;                                           \
                if (ixj > i) {                                                  \
                    uint64_t a = lds[i], bb = lds[ixj];                         \
                    bool up = ((i & k) == 0);                                   \
                    if ((a > bb) == up) { lds[i] = bb; lds[ixj] = a; }          \
                }                                                               \
            }                                                                   \
            __syncthreads();                                                    \
        }                                                                       \
    }

__global__ void k_fused(const float* __restrict__ sc, int* __restrict__ out,
                        uint32_t* hist, uint32_t* Hrow, int* Bs, uint32_t* pcur,
                        uint32_t* pse, uint64_t* cand, float* rv, uint32_t* ri) {
    cg::grid_group grid = cg::this_grid();
    __shared__ uint64_t smem64[4096]; // 32 KiB arena, re-purposed per phase
    uint32_t* smem32 = (uint32_t*)smem64;

    const int tid = (int)threadIdx.x;
    const int bid = (int)blockIdx.x;

    // ---- phase 0: zero hist ----
    for (int i = bid * BLOCK_THREADS + tid; i < BROWS * NBUCK;
         i += GRID_BLOCKS * BLOCK_THREADS) hist[i] = 0u;
    grid.sync();

    // ---- phase 1: hist (blocks 0..31; R8-proven LDS-privatized) ----
    if (bid < BROWS * 8) {
        uint32_t* h = smem32;
        for (int t = tid; t < NBUCK; t += BLOCK_THREADS) h[t] = 0u;
        __syncthreads();
        int row  = bid >> 3;
        int part = bid & 7;
        const int CHUNK = NCOLS / 8; // 16384
        const float* p = sc + row * NCOLS + part * CHUNK;
        for (int c = tid; c < CHUNK; c += BLOCK_THREADS) {
            uint32_t u = orderable(p[c]);
            atomicAdd(&h[u >> USHIFT], 1u);
        }
        __syncthreads();
        uint32_t* g = hist + (row << HIST_BITS);
        for (int t = tid; t < NBUCK; t += BLOCK_THREADS) {
            uint32_t v = h[t];
            if (v) atomicAdd(&g[t], v);
        }
    }
    grid.sync();

    // ---- phase 2: thresh (blocks 0..3; R11-proven parallel quota walk,
    //      width-adapted: 512 threads x 16 buckets) ----
    if (bid < BROWS) {
        uint32_t* inc = smem32; // 512 u32
        int row = bid;
        const uint32_t* h = hist + (row << HIST_BITS);
        int bhi = NBUCK - 1 - tid * 16;
        uint32_t run = 0;
        for (int k = 0; k < 16; ++k) run += h[bhi - k];
        inc[tid] = run;
        __syncthreads();
        for (int off = 1; off < BLOCK_THREADS; off <<= 1) {
            uint32_t v = (tid >= off) ? inc[tid - off] : 0u;
            __syncthreads();
            inc[tid] += v;
            __syncthreads();
        }
        uint32_t excl = inc[tid] - run;
        if (tid == 0) {
            Bs[row * NPART + 0] = NBUCK;
            pcur[row * NPART + 0] = 0u;
            pse[row * (NPART + 1) + 0] = 0u;
        }
        uint32_t cum = excl;
        for (int k = 0; k < 16; ++k) {
            int b = bhi - k;
            uint32_t prev = cum;
            cum += h[b];
            if (prev < (uint32_t)MREF) {
                uint32_t plo = prev / PQUOTA + 1u;
                uint32_t phi = cum / PQUOTA;
                if (phi > (uint32_t)(NPART - 1)) phi = (uint32_t)(NPART - 1);
                for (uint32_t p = plo; p <= phi; ++p) {
                    uint32_t st = prev; if (st > (uint32_t)CAP) st = (uint32_t)CAP;
                    Bs[row * NPART + p] = b;
                    pcur[row * NPART + p] = st;
                    pse[row * (NPART + 1) + p] = st;
                }
                if (cum >= (uint32_t)MREF) {
                    uint32_t T = cum; if (T > (uint32_t)CAP) T = (uint32_t)CAP;
                    Hrow[row] = (uint32_t)b;
                    pse[row * (NPART + 1) + NPART] = T;
                    uint32_t pstart = cum / PQUOTA + 1u;
                    for (uint32_t p = pstart; p < (uint32_t)NPART; ++p) {
                        Bs[row * NPART + p] = b - 1;
                        pcur[row * NPART + p] = T;
                        pse[row * (NPART + 1) + p] = T;
                    }
                }
            }
        }
    }
    grid.sync();

    // ---- phase 3: compact (all blocks; R8-proven, 2 elems/thread) ----
    {
        int* bsL        = (int*)smem32;      // NPART
        uint32_t* cntP  = smem32 + NPART;    // NPART
        uint32_t* baseP = smem32 + 2 * NPART;// NPART
        int row  = bid >> 7;
        int base = (bid & 127) << 10;
        uint32_t H = Hrow[row];
        if (tid < NPART) { bsL[tid] = Bs[row * NPART + tid]; cntP[tid] = 0u; }
        __syncthreads();
        const float* p = sc + row * NCOLS + base;
        uint32_t myu[2], mycol[2], myr[2];
        int myp[2];
        uint32_t n = 0;
        for (int k = 0; k < 2; ++k) {
            int c = tid + (k << 9);
            uint32_t u = orderable(p[c]);
            uint32_t b = u >> USHIFT;
            if (b >= H) {
                int pp2 = 0;
                for (int q = 1; q < NPART; ++q) pp2 += ((int)b <= bsL[q]) ? 1 : 0;
                myu[n] = u; mycol[n] = (uint32_t)(base + c); myp[n] = pp2;
                myr[n] = atomicAdd(&cntP[pp2], 1u);
                ++n;
            }
        }
        __syncthreads();
        if (tid < NPART)
            baseP[tid] = atomicAdd(&pcur[row * NPART + tid], cntP[tid]);
        __syncthreads();
        uint64_t* cr = cand + (size_t)row * CAP;
        for (uint32_t k = 0; k < n; ++k) {
            uint32_t idx = baseP[myp[k]] + myr[k];
            if (idx < (uint32_t)CAP)
                cr[idx] = ((uint64_t)(~myu[k]) << 32) | mycol[k];
        }
    }
    grid.sync();

    // ---- phase 4: psort (blocks 0..127; R11-proven size-adaptive bitonic) ----
    if (bid < BROWS * NPART) {
        uint64_t* lds = smem64; // PARTCAP u64 = 8 KiB
        int row = bid >> 5;
        int pp2 = bid & 31;
        uint32_t start = pse[row * (NPART + 1) + pp2];
        uint32_t end   = pse[row * (NPART + 1) + pp2 + 1];
        if (end > (uint32_t)CAP) end = (uint32_t)CAP;
        uint32_t n = (end > start) ? (end - start) : 0u;
        if (n > (uint32_t)PARTCAP) n = (uint32_t)PARTCAP;
        uint64_t* seg = cand + (size_t)row * CAP + start;
        if (n <= 256u) {
            BITONIC_SORT(256)
        } else if (n <= 512u) {
            BITONIC_SORT(512)
        } else {
            BITONIC_SORT(1024)
        }
        for (uint32_t i = tid; i < n; i += BLOCK_THREADS) {
            uint32_t gpos = start + i;
            if (gpos < (uint32_t)MREF) {
                uint64_t key = lds[i];
                uint32_t u = ~(uint32_t)(key >> 32);
                rv[row * MREF + gpos] = unorderable(u);
                ri[row * MREF + gpos] = (uint32_t)(key & 0xFFFFFFFFu);
            }
        }
    }
    grid.sync();

    // ---- phase 5: map (all blocks; 2 cols/thread via duplicated calls) ----
    {
        float* srv = (float*)smem64; // MREF f32 = 16 KiB
        int row  = bid >> 7;
        int base = (bid & 127) << 10;
        const float* rvr = rv + row * MREF;
        for (int t = tid; t < MREF; t += BLOCK_THREADS) srv[t] = rvr[t];
        __syncthreads();
        const float* scr = sc + row * NCOLS;
        const uint32_t* rir = ri + row * MREF;
        int* outr = out + row * NCOLS;
        map_one(scr, srv, rir, outr, base + tid);
        map_one(scr, srv, rir, outr, base + 512 + tid);
    }
}

extern "C" void kernel_launch(void* const* d_in, const int* in_sizes, int n_in,
                              void* d_out, int out_size, void* d_ws, size_t ws_size,
                              hipStream_t stream) {
    const float* sc = (const float*)d_in[0];
    int* out = (int*)d_out;
    char* w = (char*)d_ws;

    // ws layout (bytes):
    //   hist [4*8192 u32] @ 0       (131072) <- phase 0
    //   Hrow [4 u32]      @ 131072  (pad 128)
    //   Bs   [4*32 int]   @ 131200  (512)
    //   pcur [4*32 u32]   @ 131712  (512)
    //   pse  [4*33 u32]   @ 132224  (528, pad 640)
    //   cand [4*6144 u64] @ 132864  (196608)
    //   rv   [4*4096 f32] @ 329472  (65536)
    //   ri   [4*4096 u32] @ 395008  (65536)  -> total 460544
    uint32_t* hist = (uint32_t*)w;
    uint32_t* Hrow = (uint32_t*)(w + 131072);
    int*      Bs   = (int*)     (w + 131200);
    uint32_t* pcur = (uint32_t*)(w + 131712);
    uint32_t* pse  = (uint32_t*)(w + 132224);
    uint64_t* cand = (uint64_t*)(w + 132864);
    float*    rv   = (float*)   (w + 329472);
    uint32_t* ri   = (uint32_t*)(w + 395008);

    void* args[] = {(void*)&sc, (void*)&out, (void*)&hist, (void*)&Hrow, (void*)&Bs,
                    (void*)&pcur, (void*)&pse, (void*)&cand, (void*)&rv, (void*)&ri};
    hipLaunchCooperativeKernel((const void*)k_fused, dim3(GRID_BLOCKS),
                               dim3(BLOCK_THREADS), args, 0, stream);
}

// Round 13
// 62.489 us; speedup vs baseline: 4.8774x; 4.8774x over previous
//
#include <hip/hip_runtime.h>
#include <stdint.h>

// Problem constants (fixed by reference: scores (4, 131072) f32, m=4096, tau=1)
#define BROWS 4
#define NCOLS 131072           // 2^17
#define MREF  4096
#define HIST_BITS 13
#define NBUCK (1 << HIST_BITS) // 8192
#define USHIFT (32 - HIST_BITS)
#define CAP 6144               // candidates per row (<= 4095 + threshold-bucket count)
#define HIST_BLK_PER_ROW 16
#define NPART 32
#define PQUOTA 192             // quota spacing (R8-proven: max partition < 1024)
#define PARTCAP 1024           // max bitonic size

__device__ __forceinline__ uint32_t orderable(float f) {
    uint32_t u = __float_as_uint(f);
    return (u & 0x80000000u) ? ~u : (u | 0x80000000u);
}
__device__ __forceinline__ float unorderable(uint32_t u) {
    uint32_t b = (u & 0x80000000u) ? (u & 0x7FFFFFFFu) : ~u;
    return __uint_as_float(b);
}
// Device-coherent (agent-scope) load: bypasses possibly-stale local L2 so the
// last-arriving block can read other XCDs' atomic results within one kernel.
__device__ __forceinline__ uint32_t gload(const uint32_t* p) {
    return __hip_atomic_load(p, __ATOMIC_RELAXED, __HIP_MEMORY_SCOPE_AGENT);
}

// Fused hist+thresh: 16 blocks/row x 512 threads. Each block builds an LDS
// histogram of its 8192-element chunk, atomically flushes to global, then the
// LAST block per row (arrival counter) runs the R12-run-proven 512-thread
// quota walk inline over agent-scope hist loads. No spin, no deadlock.
__global__ void k_histthresh(const float* __restrict__ sc, uint32_t* __restrict__ hist,
                             uint32_t* __restrict__ cnt, uint32_t* __restrict__ Hrow,
                             int* __restrict__ Bs, uint32_t* __restrict__ pcur,
                             uint32_t* __restrict__ pse) {
    __shared__ uint32_t h[NBUCK]; // 32 KiB
    __shared__ uint32_t inc[512];
    __shared__ uint32_t lastflag;
    const int tid = (int)threadIdx.x;
    for (int t = tid; t < NBUCK; t += 512) h[t] = 0u;
    __syncthreads();
    int row  = (int)blockIdx.x / HIST_BLK_PER_ROW;
    int part = (int)blockIdx.x % HIST_BLK_PER_ROW;
    const int CHUNK = NCOLS / HIST_BLK_PER_ROW; // 8192
    const float* p = sc + row * NCOLS + part * CHUNK;
    for (int c = tid; c < CHUNK; c += 512) {
        uint32_t u = orderable(p[c]);
        atomicAdd(&h[u >> USHIFT], 1u);
    }
    __syncthreads();
    uint32_t* g = hist + (row << HIST_BITS);
    for (int t = tid; t < NBUCK; t += 512) {
        uint32_t v = h[t];
        if (v) atomicAdd(&g[t], v);
    }
    // __syncthreads drains each thread's outstanding atomics (vmcnt(0)) before
    // the arrival-counter bump -> flushes happen-before the counter value.
    __syncthreads();
    if (tid == 0) {
        __threadfence();
        lastflag = atomicAdd(&cnt[row * 32], 1u); // 128B-strided counters
    }
    __syncthreads();
    if (lastflag != (uint32_t)(HIST_BLK_PER_ROW - 1)) return;
    __threadfence(); // acquire side

    // ---- thresh walk (R12 phase-2 code, runtime-proven; h[] -> gload) ----
    int bhi = NBUCK - 1 - tid * 16;
    uint32_t run = 0;
    for (int k = 0; k < 16; ++k) run += gload(&g[bhi - k]);
    inc[tid] = run;
    __syncthreads();
    for (int off = 1; off < 512; off <<= 1) {
        uint32_t v = (tid >= off) ? inc[tid - off] : 0u;
        __syncthreads();
        inc[tid] += v;
        __syncthreads();
    }
    uint32_t excl = inc[tid] - run;
    if (tid == 0) {
        Bs[row * NPART + 0] = NBUCK; // sentinel, unused in membership test
        pcur[row * NPART + 0] = 0u;
        pse[row * (NPART + 1) + 0] = 0u;
    }
    uint32_t cum = excl;
    for (int k = 0; k < 16; ++k) {
        int b = bhi - k;
        uint32_t prev = cum;
        cum += gload(&g[b]);
        if (prev < (uint32_t)MREF) {
            uint32_t plo = prev / PQUOTA + 1u;
            uint32_t phi = cum / PQUOTA;
            if (phi > (uint32_t)(NPART - 1)) phi = (uint32_t)(NPART - 1);
            for (uint32_t pq = plo; pq <= phi; ++pq) {
                uint32_t st = prev; if (st > (uint32_t)CAP) st = (uint32_t)CAP;
                Bs[row * NPART + pq] = b;
                pcur[row * NPART + pq] = st;
                pse[row * (NPART + 1) + pq] = st;
            }
            if (cum >= (uint32_t)MREF) {
                uint32_t T = cum; if (T > (uint32_t)CAP) T = (uint32_t)CAP;
                Hrow[row] = (uint32_t)b;
                pse[row * (NPART + 1) + NPART] = T;
                uint32_t pstart = cum / PQUOTA + 1u;
                for (uint32_t pq = pstart; pq < (uint32_t)NPART; ++pq) {
                    Bs[row * NPART + pq] = b - 1;
                    pcur[row * NPART + pq] = T;
                    pse[row * (NPART + 1) + pq] = T;
                }
            }
        }
    }
}

// R11-exact: per-partition LDS counts + NPART global reserves, scatter to cand.
__global__ void k_compact(const float* __restrict__ sc, const uint32_t* __restrict__ Hrow,
                          const int* __restrict__ Bs, uint32_t* __restrict__ pcur,
                          uint64_t* __restrict__ cand) {
    __shared__ int bsL[NPART];
    __shared__ uint32_t cntP[NPART];
    __shared__ uint32_t baseP[NPART];
    int row = blockIdx.x >> 7;
    int base = (blockIdx.x & 127) << 10;
    uint32_t H = Hrow[row];
    if (threadIdx.x < NPART) {
        bsL[threadIdx.x] = Bs[row * NPART + threadIdx.x];
        cntP[threadIdx.x] = 0u;
    }
    __syncthreads();
    const float* p = sc + row * NCOLS + base;

    uint32_t myu[4], mycol[4], myr[4];
    int myp[4];
    uint32_t n = 0;
    for (int k = 0; k < 4; ++k) {
        int c = (int)threadIdx.x + (k << 8);
        uint32_t u = orderable(p[c]);
        uint32_t b = u >> USHIFT;
        if (b >= H) {
            int pp = 0;
            for (int q = 1; q < NPART; ++q) pp += ((int)b <= bsL[q]) ? 1 : 0;
            myu[n] = u; mycol[n] = (uint32_t)(base + c); myp[n] = pp;
            myr[n] = atomicAdd(&cntP[pp], 1u);
            ++n;
        }
    }
    __syncthreads();
    if (threadIdx.x < NPART)
        baseP[threadIdx.x] = atomicAdd(&pcur[row * NPART + threadIdx.x], cntP[threadIdx.x]);
    __syncthreads();
    uint64_t* cr = cand + (size_t)row * CAP;
    for (uint32_t k = 0; k < n; ++k) {
        uint32_t idx = baseP[myp[k]] + myr[k];
        if (idx < (uint32_t)CAP)
            cr[idx] = ((uint64_t)(~myu[k]) << 32) | mycol[k];
    }
}

// R11-exact: size-adaptive bitonic (block-uniform n).
#define BITONIC_SORT(PP)                                                        \
    for (uint32_t i = threadIdx.x; i < (uint32_t)(PP); i += blockDim.x)         \
        lds[i] = (i < n) ? seg[i] : ~0ULL;                                      \
    __syncthreads();                                                            \
    for (uint32_t k = 2; k <= (uint32_t)(PP); k <<= 1) {                        \
        for (uint32_t j = k >> 1; j > 0; j >>= 1) {                             \
            for (uint32_t i = threadIdx.x; i < (uint32_t)(PP); i += blockDim.x) { \
                uint32_t ixj = i ^ j;                                           \
                if (ixj > i) {                                                  \
                    uint64_t a = lds[i], bb = lds[ixj];                         \
                    bool up = ((i & k) == 0);                                   \
                    if ((a > bb) == up) { lds[i] = bb; lds[ixj] = a; }          \
                }                                                               \
            }                                                                   \
            __syncthreads();                                                    \
        }                                                                       \
    }

__global__ void k_psort(const uint32_t* __restrict__ pse, uint64_t* __restrict__ cand,
                        float* __restrict__ rv, uint32_t* __restrict__ ri) {
    __shared__ uint64_t lds[PARTCAP]; // 8 KiB
    int row = blockIdx.x >> 5;
    int pp  = blockIdx.x & 31;
    uint32_t start = pse[row * (NPART + 1) + pp];
    uint32_t end   = pse[row * (NPART + 1) + pp + 1];
    if (end > (uint32_t)CAP) end = (uint32_t)CAP;
    uint32_t n = (end > start) ? (end - start) : 0u;
    if (n > (uint32_t)PARTCAP) n = (uint32_t)PARTCAP;
    uint64_t* seg = cand + (size_t)row * CAP + start;
    if (n <= 256u) {
        BITONIC_SORT(256)
    } else if (n <= 512u) {
        BITONIC_SORT(512)
    } else {
        BITONIC_SORT(1024)
    }
    for (uint32_t i = threadIdx.x; i < n; i += blockDim.x) {
        uint32_t gpos = start + i;
        if (gpos < (uint32_t)MREF) {
            uint64_t key = lds[i];
            uint32_t u = ~(uint32_t)(key >> 32);
            rv[row * MREF + gpos] = unorderable(u);
            ri[row * MREF + gpos] = (uint32_t)(key & 0xFFFFFFFFu);
        }
    }
}

// R11-exact (1 col/thread; 4-col inner-loop variant crashes the clang-22
// frontend): nearest-ref mapping with float32 tie emulation.
__global__ void k_map(const float* __restrict__ sc, const float* __restrict__ rv,
                      const uint32_t* __restrict__ ri, int* __restrict__ out) {
    __shared__ float srv[MREF]; // 16 KiB
    int row = blockIdx.x >> 9;
    int col = ((blockIdx.x & 511) << 8) + threadIdx.x;
    const float* rvr = rv + row * MREF;
    for (int t = threadIdx.x; t < MREF; t += blockDim.x) srv[t] = rvr[t];
    __syncthreads();

    float s = sc[row * NCOLS + col];
    // first j with srv[j] <= s (srv descending)
    int lo = 0, hi = MREF;
    while (lo < hi) { int mid = (lo + hi) >> 1; if (srv[mid] <= s) hi = mid; else lo = mid + 1; }
    int p = lo, jmin;
    if (p == 0) jmin = 0;
    else if (p == MREF) jmin = MREF - 1;
    else {
        float dp = fabsf(s - srv[p]);
        float dm = fabsf(s - srv[p - 1]);
        jmin = (dm <= dp) ? (p - 1) : p; // tie -> smaller j (argmax-first)
    }
    float pmax = -fabsf(s - srv[jmin]);
    int jans = jmin;
    // exp-level tie merge: exp(pw - pmax) rounds to 1.0f => equal softmax prob,
    // argmax picks the smallest such j; winner set is contiguous.
    for (int j = jmin - 1; j >= 0; --j) {
        float pw = -fabsf(s - srv[j]);
        if (expf(pw - pmax) == 1.0f) jans = j; else break;
    }
    out[row * NCOLS + col] = (int)ri[row * MREF + jans];
}

extern "C" void kernel_launch(void* const* d_in, const int* in_sizes, int n_in,
                              void* d_out, int out_size, void* d_ws, size_t ws_size,
                              hipStream_t stream) {
    const float* sc = (const float*)d_in[0];
    int* out = (int*)d_out;
    char* w = (char*)d_ws;

    // ws layout (bytes):
    //   hist [4*8192 u32]  @ 0       (131072) <- memset
    //   cnt  [4*32 u32]    @ 131072  (512)    <- memset (128B-strided counters)
    //   Hrow [4 u32]       @ 131584  (pad 128)
    //   Bs   [4*32 int]    @ 131712  (512)
    //   pcur [4*32 u32]    @ 132224  (512)
    //   pse  [4*33 u32]    @ 132736  (528, pad 640)
    //   cand [4*6144 u64]  @ 133376  (196608)
    //   rv   [4*4096 f32]  @ 329984  (65536)
    //   ri   [4*4096 u32]  @ 395520  (65536)  -> total 461056
    uint32_t* hist = (uint32_t*)w;
    uint32_t* cnt  = (uint32_t*)(w + 131072);
    uint32_t* Hrow = (uint32_t*)(w + 131584);
    int*      Bs   = (int*)     (w + 131712);
    uint32_t* pcur = (uint32_t*)(w + 132224);
    uint32_t* pse  = (uint32_t*)(w + 132736);
    uint64_t* cand = (uint64_t*)(w + 133376);
    float*    rv   = (float*)   (w + 329984);
    uint32_t* ri   = (uint32_t*)(w + 395520);

    hipMemsetAsync(w, 0, 131072 + 512, stream);
    k_histthresh<<<BROWS * HIST_BLK_PER_ROW, 512, 0, stream>>>(sc, hist, cnt, Hrow, Bs, pcur, pse);
    k_compact   <<<512, 256, 0, stream>>>(sc, Hrow, Bs, pcur, cand);
    k_psort     <<<BROWS * NPART, 512, 0, stream>>>(pse, cand, rv, ri);
    k_map       <<<BROWS * 512, 256, 0, stream>>>(sc, rv, ri, out);
}

// Round 14
// 61.409 us; speedup vs baseline: 4.9632x; 1.0176x over previous
//
#include <hip/hip_runtime.h>
#include <stdint.h>

// Problem constants (fixed by reference: scores (4, 131072) f32, m=4096, tau=1)
#define BROWS 4
#define NCOLS 131072           // 2^17
#define MREF  4096
#define HIST_BITS 13
#define NBUCK (1 << HIST_BITS) // 8192
#define USHIFT (32 - HIST_BITS)
#define CAP 6144               // candidates per row (<= 4095 + threshold-bucket count)
#define HIST_BLK_PER_ROW 16
#define NPART 32
#define PQUOTA 192             // quota spacing (R8-proven: max partition < 1024)
#define PARTCAP 1024           // max bitonic size

__device__ __forceinline__ uint32_t orderable(float f) {
    uint32_t u = __float_as_uint(f);
    return (u & 0x80000000u) ? ~u : (u | 0x80000000u);
}
__device__ __forceinline__ float unorderable(uint32_t u) {
    uint32_t b = (u & 0x80000000u) ? (u & 0x7FFFFFFFu) : ~u;
    return __uint_as_float(b);
}
// Device-coherent (agent-scope) load: bypasses possibly-stale local L2 so the
// last-arriving block can read other XCDs' atomic results within one kernel.
__device__ __forceinline__ uint32_t gload(const uint32_t* p) {
    return __hip_atomic_load(p, __ATOMIC_RELAXED, __HIP_MEMORY_SCOPE_AGENT);
}

// Fused hist+thresh (R13-proven): 16 blocks/row x 512 threads, float4 loads.
__global__ void k_histthresh(const float* __restrict__ sc, uint32_t* __restrict__ hist,
                             uint32_t* __restrict__ cnt, uint32_t* __restrict__ Hrow,
                             int* __restrict__ Bs, uint32_t* __restrict__ pcur,
                             uint32_t* __restrict__ pse) {
    __shared__ uint32_t h[NBUCK]; // 32 KiB
    __shared__ uint32_t inc[512];
    __shared__ uint32_t lastflag;
    const int tid = (int)threadIdx.x;
    for (int t = tid; t < NBUCK; t += 512) h[t] = 0u;
    __syncthreads();
    int row  = (int)blockIdx.x / HIST_BLK_PER_ROW;
    int part = (int)blockIdx.x % HIST_BLK_PER_ROW;
    const int CHUNK = NCOLS / HIST_BLK_PER_ROW; // 8192
    const float4* p4 = (const float4*)(sc + row * NCOLS + part * CHUNK);
    for (int c = tid; c < CHUNK / 4; c += 512) { // 4 iterations
        float4 v = p4[c];
        atomicAdd(&h[orderable(v.x) >> USHIFT], 1u);
        atomicAdd(&h[orderable(v.y) >> USHIFT], 1u);
        atomicAdd(&h[orderable(v.z) >> USHIFT], 1u);
        atomicAdd(&h[orderable(v.w) >> USHIFT], 1u);
    }
    __syncthreads();
    uint32_t* g = hist + (row << HIST_BITS);
    for (int t = tid; t < NBUCK; t += 512) {
        uint32_t v = h[t];
        if (v) atomicAdd(&g[t], v);
    }
    // __syncthreads drains each thread's outstanding atomics before the
    // arrival-counter bump -> flushes happen-before the counter value.
    __syncthreads();
    if (tid == 0) {
        __threadfence();
        lastflag = atomicAdd(&cnt[row * 32], 1u); // 128B-strided counters
    }
    __syncthreads();
    if (lastflag != (uint32_t)(HIST_BLK_PER_ROW - 1)) return;
    __threadfence(); // acquire side

    // ---- thresh walk (R13-run-proven) ----
    int bhi = NBUCK - 1 - tid * 16;
    uint32_t run = 0;
    for (int k = 0; k < 16; ++k) run += gload(&g[bhi - k]);
    inc[tid] = run;
    __syncthreads();
    for (int off = 1; off < 512; off <<= 1) {
        uint32_t v = (tid >= off) ? inc[tid - off] : 0u;
        __syncthreads();
        inc[tid] += v;
        __syncthreads();
    }
    uint32_t excl = inc[tid] - run;
    if (tid == 0) {
        Bs[row * NPART + 0] = NBUCK; // sentinel, unused in membership test
        pcur[row * NPART + 0] = 0u;
        pse[row * (NPART + 1) + 0] = 0u;
    }
    uint32_t cum = excl;
    for (int k = 0; k < 16; ++k) {
        int b = bhi - k;
        uint32_t prev = cum;
        cum += gload(&g[b]);
        if (prev < (uint32_t)MREF) {
            uint32_t plo = prev / PQUOTA + 1u;
            uint32_t phi = cum / PQUOTA;
            if (phi > (uint32_t)(NPART - 1)) phi = (uint32_t)(NPART - 1);
            for (uint32_t pq = plo; pq <= phi; ++pq) {
                uint32_t st = prev; if (st > (uint32_t)CAP) st = (uint32_t)CAP;
                Bs[row * NPART + pq] = b;
                pcur[row * NPART + pq] = st;
                pse[row * (NPART + 1) + pq] = st;
            }
            if (cum >= (uint32_t)MREF) {
                uint32_t T = cum; if (T > (uint32_t)CAP) T = (uint32_t)CAP;
                Hrow[row] = (uint32_t)b;
                pse[row * (NPART + 1) + NPART] = T;
                uint32_t pstart = cum / PQUOTA + 1u;
                for (uint32_t pq = pstart; pq < (uint32_t)NPART; ++pq) {
                    Bs[row * NPART + pq] = b - 1;
                    pcur[row * NPART + pq] = T;
                    pse[row * (NPART + 1) + pq] = T;
                }
            }
        }
    }
}

// R11 semantics, widened: 1024 blocks x 512 threads, 1 element/thread
// (scalars, no per-thread arrays). Max TLP for the 2 MB read.
__global__ void k_compact(const float* __restrict__ sc, const uint32_t* __restrict__ Hrow,
                          const int* __restrict__ Bs, uint32_t* __restrict__ pcur,
                          uint64_t* __restrict__ cand) {
    __shared__ int bsL[NPART];
    __shared__ uint32_t cntP[NPART];
    __shared__ uint32_t baseP[NPART];
    int row  = (int)blockIdx.x >> 8;
    int base = ((int)blockIdx.x & 255) << 9;
    uint32_t H = Hrow[row];
    if (threadIdx.x < NPART) {
        bsL[threadIdx.x] = Bs[row * NPART + threadIdx.x];
        cntP[threadIdx.x] = 0u;
    }
    __syncthreads();

    float s = sc[row * NCOLS + base + (int)threadIdx.x];
    uint32_t u = orderable(s);
    uint32_t b = u >> USHIFT;
    bool keep = (b >= H);
    int pp = 0;
    uint32_t rank = 0;
    if (keep) {
        for (int q = 1; q < NPART; ++q) pp += ((int)b <= bsL[q]) ? 1 : 0;
        rank = atomicAdd(&cntP[pp], 1u);
    }
    __syncthreads();
    if (threadIdx.x < NPART)
        baseP[threadIdx.x] = atomicAdd(&pcur[row * NPART + threadIdx.x], cntP[threadIdx.x]);
    __syncthreads();
    if (keep) {
        uint32_t idx = baseP[pp] + rank;
        if (idx < (uint32_t)CAP)
            cand[(size_t)row * CAP + idx] =
                ((uint64_t)(~u) << 32) | (uint32_t)(base + (int)threadIdx.x);
    }
}

// R11-exact: size-adaptive bitonic (block-uniform n).
#define BITONIC_SORT(PP)                                                        \
    for (uint32_t i = threadIdx.x; i < (uint32_t)(PP); i += blockDim.x)         \
        lds[i] = (i < n) ? seg[i] : ~0ULL;                                      \
    __syncthreads();                                                            \
    for (uint32_t k = 2; k <= (uint32_t)(PP); k <<= 1) {                        \
        for (uint32_t j = k >> 1; j > 0; j >>= 1) {                             \
            for (uint32_t i = threadIdx.x; i < (uint32_t)(PP); i += blockDim.x) { \
                uint32_t ixj = i ^ j;                                           \
                if (ixj > i) {                                                  \
                    uint64_t a = lds[i], bb = lds[ixj];                         \
                    bool up = ((i & k) == 0);                                   \
                    if ((a > bb) == up) { lds[i] = bb; lds[ixj] = a; }          \
                }                                                               \
            }                                                                   \
            __syncthreads();                                                    \
        }                                                                       \
    }

__global__ void k_psort(const uint32_t* __restrict__ pse, uint64_t* __restrict__ cand,
                        float* __restrict__ rv, uint32_t* __restrict__ ri) {
    __shared__ uint64_t lds[PARTCAP]; // 8 KiB
    int row = blockIdx.x >> 5;
    int pp  = blockIdx.x & 31;
    uint32_t start = pse[row * (NPART + 1) + pp];
    uint32_t end   = pse[row * (NPART + 1) + pp + 1];
    if (end > (uint32_t)CAP) end = (uint32_t)CAP;
    uint32_t n = (end > start) ? (end - start) : 0u;
    if (n > (uint32_t)PARTCAP) n = (uint32_t)PARTCAP;
    uint64_t* seg = cand + (size_t)row * CAP + start;
    if (n <= 256u) {
        BITONIC_SORT(256)
    } else if (n <= 512u) {
        BITONIC_SORT(512)
    } else {
        BITONIC_SORT(1024)
    }
    for (uint32_t i = threadIdx.x; i < n; i += blockDim.x) {
        uint32_t gpos = start + i;
        if (gpos < (uint32_t)MREF) {
            uint64_t key = lds[i];
            uint32_t u = ~(uint32_t)(key >> 32);
            rv[row * MREF + gpos] = unorderable(u);
            ri[row * MREF + gpos] = (uint32_t)(key & 0xFFFFFFFFu);
        }
    }
}

// Per-thread body R11-exact (1 col/thread; 4-col loop crashes clang-22).
// Widened: 1024 blocks x 512 threads -> half the srv-staging traffic.
__global__ void k_map(const float* __restrict__ sc, const float* __restrict__ rv,
                      const uint32_t* __restrict__ ri, int* __restrict__ out) {
    __shared__ float srv[MREF]; // 16 KiB
    int row = (int)blockIdx.x >> 8;
    int col = (((int)blockIdx.x & 255) << 9) + (int)threadIdx.x;
    const float* rvr = rv + row * MREF;
    for (int t = threadIdx.x; t < MREF; t += blockDim.x) srv[t] = rvr[t];
    __syncthreads();

    float s = sc[row * NCOLS + col];
    // first j with srv[j] <= s (srv descending)
    int lo = 0, hi = MREF;
    while (lo < hi) { int mid = (lo + hi) >> 1; if (srv[mid] <= s) hi = mid; else lo = mid + 1; }
    int p = lo, jmin;
    if (p == 0) jmin = 0;
    else if (p == MREF) jmin = MREF - 1;
    else {
        float dp = fabsf(s - srv[p]);
        float dm = fabsf(s - srv[p - 1]);
        jmin = (dm <= dp) ? (p - 1) : p; // tie -> smaller j (argmax-first)
    }
    float pmax = -fabsf(s - srv[jmin]);
    int jans = jmin;
    // exp-level tie merge: exp(pw - pmax) rounds to 1.0f => equal softmax prob,
    // argmax picks the smallest such j; winner set is contiguous.
    for (int j = jmin - 1; j >= 0; --j) {
        float pw = -fabsf(s - srv[j]);
        if (expf(pw - pmax) == 1.0f) jans = j; else break;
    }
    out[row * NCOLS + col] = (int)ri[row * MREF + jans];
}

extern "C" void kernel_launch(void* const* d_in, const int* in_sizes, int n_in,
                              void* d_out, int out_size, void* d_ws, size_t ws_size,
                              hipStream_t stream) {
    const float* sc = (const float*)d_in[0];
    int* out = (int*)d_out;
    char* w = (char*)d_ws;

    // ws layout (bytes):
    //   hist [4*8192 u32]  @ 0       (131072) <- memset
    //   cnt  [4*32 u32]    @ 131072  (512)    <- memset (128B-strided counters)
    //   Hrow [4 u32]       @ 131584  (pad 128)
    //   Bs   [4*32 int]    @ 131712  (512)
    //   pcur [4*32 u32]    @ 132224  (512)
    //   pse  [4*33 u32]    @ 132736  (528, pad 640)
    //   cand [4*6144 u64]  @ 133376  (196608)
    //   rv   [4*4096 f32]  @ 329984  (65536)
    //   ri   [4*4096 u32]  @ 395520  (65536)  -> total 461056
    uint32_t* hist = (uint32_t*)w;
    uint32_t* cnt  = (uint32_t*)(w + 131072);
    uint32_t* Hrow = (uint32_t*)(w + 131584);
    int*      Bs   = (int*)     (w + 131712);
    uint32_t* pcur = (uint32_t*)(w + 132224);
    uint32_t* pse  = (uint32_t*)(w + 132736);
    uint64_t* cand = (uint64_t*)(w + 133376);
    float*    rv   = (float*)   (w + 329984);
    uint32_t* ri   = (uint32_t*)(w + 395520);

    hipMemsetAsync(w, 0, 131072 + 512, stream);
    k_histthresh<<<BROWS * HIST_BLK_PER_ROW, 512, 0, stream>>>(sc, hist, cnt, Hrow, Bs, pcur, pse);
    k_compact   <<<1024, 512, 0, stream>>>(sc, Hrow, Bs, pcur, cand);
    k_psort     <<<BROWS * NPART, 512, 0, stream>>>(pse, cand, rv, ri);
    k_map       <<<1024, 512, 0, stream>>>(sc, rv, ri, out);
}